// Round 1
// baseline (270.538 us; speedup 1.0000x reference)
//
#include <hip/hip_runtime.h>
#include <hip/hip_bf16.h>
#include <math.h>

#define B_  32
#define C_  256
#define HW_ 4096
#define K_  5

typedef __hip_bfloat16 bf16;

// ---------- dtype-flexible load/store ----------
template<bool BF>
__device__ inline float LD(const void* p, size_t i) {
    if (BF) return __bfloat162float(((const bf16*)p)[i]);
    return ((const float*)p)[i];
}
template<bool BF>
__device__ inline void ST(void* p, size_t i, float v) {
    if (BF) ((bf16*)p)[i] = __float2bfloat16(v);
    else    ((float*)p)[i] = v;
}

// ---------- block reductions (256 threads = 4 waves) ----------
__device__ inline float blk_sum(float v, float* sh) {
    for (int o = 32; o > 0; o >>= 1) v += __shfl_down(v, o, 64);
    int w = threadIdx.x >> 6;
    __syncthreads();                       // protect sh from previous use
    if ((threadIdx.x & 63) == 0) sh[w] = v;
    __syncthreads();
    return sh[0] + sh[1] + sh[2] + sh[3];
}
__device__ inline float blk_max(float v, float* sh) {
    for (int o = 32; o > 0; o >>= 1) v = fmaxf(v, __shfl_down(v, o, 64));
    int w = threadIdx.x >> 6;
    __syncthreads();
    if ((threadIdx.x & 63) == 0) sh[w] = v;
    __syncthreads();
    return fmaxf(fmaxf(sh[0], sh[1]), fmaxf(sh[2], sh[3]));
}

// ---------- 0: dtype detector ----------
__global__ void k_detect(const void* feat, int* flag) {
    __shared__ int cnt;
    int t = threadIdx.x;
    if (t == 0) cnt = 0;
    __syncthreads();
    const unsigned short* u = (const unsigned short*)feat;
    int local = 0;
    for (int i = t; i < 4096; i += 256) {
        unsigned int bits = ((unsigned int)u[i]) << 16;
        float v = __uint_as_float(bits);
        float a = fabsf(v);
        if (a >= 1e-4f && a <= 100.f) local++;
    }
    atomicAdd(&cnt, local);
    __syncthreads();
    if (t == 0) *flag = (cnt > 3072) ? 1 : 0;   // bf16 ~4095, f32 ~2210
}

// ---------- 1: normalize part_queries ----------
template<bool BF>
__device__ void qnorm_body(const void* pq, float* qn, float* sh) {
    int t = threadIdx.x;  // t == c
    for (int k = 0; k < K_; k++) {
        float v = LD<BF>(pq, (size_t)k * C_ + t);
        float ss = blk_sum(v * v, sh);
        float inv = 1.0f / fmaxf(sqrtf(ss), 1e-12f);
        qn[k * C_ + t] = v * inv;
    }
}
__global__ void k_qnorm(const int* flag, const void* pq, float* qn) {
    __shared__ float sh[4];
    if (*flag) qnorm_body<true>(pq, qn, sh); else qnorm_body<false>(pq, qn, sh);
}

// ---------- 2: sim = masked (qn . feat/||feat||)/temp ----------
template<bool BF>
__device__ void sim_body(const void* feat, const void* mask, const void* temp,
                         const float* qn, float* sim, float* qL) {
    int t = threadIdx.x;
    int b = blockIdx.y;
    int n = blockIdx.x * 256 + t;
    for (int i = t; i < K_ * C_; i += 256) qL[i] = qn[i];
    __syncthreads();
    float tinv = 1.0f / fmaxf(LD<BF>(temp, 0), 0.01f);
    float mval = LD<BF>(mask, (size_t)b * HW_ + n);
    size_t base = (size_t)b * C_ * HW_ + n;
    float ss = 0, d0 = 0, d1 = 0, d2 = 0, d3 = 0, d4 = 0;
    for (int c = 0; c < C_; c++) {
        float f = LD<BF>(feat, base + (size_t)c * HW_);
        ss += f * f;
        d0 += f * qL[0 * C_ + c];
        d1 += f * qL[1 * C_ + c];
        d2 += f * qL[2 * C_ + c];
        d3 += f * qL[3 * C_ + c];
        d4 += f * qL[4 * C_ + c];
    }
    float inv = 1.0f / fmaxf(sqrtf(ss), 1e-12f);
    float sc = inv * tinv;
    bool off = !(mval > 0.f);
    size_t sb = (size_t)b * K_ * HW_ + n;
    sim[sb + 0 * HW_] = off ? -INFINITY : d0 * sc;
    sim[sb + 1 * HW_] = off ? -INFINITY : d1 * sc;
    sim[sb + 2 * HW_] = off ? -INFINITY : d2 * sc;
    sim[sb + 3 * HW_] = off ? -INFINITY : d3 * sc;
    sim[sb + 4 * HW_] = off ? -INFINITY : d4 * sc;
}
__global__ void k_sim(const int* flag, const void* feat, const void* mask,
                      const void* temp, const float* qn, float* sim) {
    __shared__ float qL[K_ * C_];
    if (*flag) sim_body<true>(feat, mask, temp, qn, sim, qL);
    else       sim_body<false>(feat, mask, temp, qn, sim, qL);
}

// ---------- 3: softmax over n per (b,k), in place, nan_to_num ----------
__global__ void k_softmax(float* sim) {
    __shared__ float sh[4];
    int row = blockIdx.x;
    int t = threadIdx.x;
    float* p = sim + (size_t)row * HW_;
    float v[16];
    float mx = -INFINITY;
    for (int i = 0; i < 16; i++) { v[i] = p[t + 256 * i]; mx = fmaxf(mx, v[i]); }
    mx = blk_max(mx, sh);
    if (mx == -INFINITY) {           // fully-masked row -> nan_to_num -> 0
        for (int i = 0; i < 16; i++) p[t + 256 * i] = 0.f;
        return;
    }
    float s = 0;
    for (int i = 0; i < 16; i++) { v[i] = __expf(v[i] - mx); s += v[i]; }
    s = blk_sum(s, sh);
    float inv = 1.0f / s;
    for (int i = 0; i < 16; i++) p[t + 256 * i] = v[i] * inv;
}

// ---------- 4: part_tokens[b,k,c] = sum_n attn*feat ----------
template<bool BF>
__device__ void pt_body(const void* feat, const float* attn, float* pt, float* sh) {
    int c = blockIdx.x, b = blockIdx.y, t = threadIdx.x;
    size_t fb = ((size_t)b * C_ + c) * HW_;
    size_t ab = (size_t)b * K_ * HW_;
    float a0 = 0, a1 = 0, a2 = 0, a3 = 0, a4 = 0;
    for (int n = t; n < HW_; n += 256) {
        float f = LD<BF>(feat, fb + n);
        a0 += f * attn[ab + 0 * HW_ + n];
        a1 += f * attn[ab + 1 * HW_ + n];
        a2 += f * attn[ab + 2 * HW_ + n];
        a3 += f * attn[ab + 3 * HW_ + n];
        a4 += f * attn[ab + 4 * HW_ + n];
    }
    a0 = blk_sum(a0, sh); a1 = blk_sum(a1, sh); a2 = blk_sum(a2, sh);
    a3 = blk_sum(a3, sh); a4 = blk_sum(a4, sh);
    if (t == 0) {
        pt[((size_t)b * K_ + 0) * C_ + c] = a0;
        pt[((size_t)b * K_ + 1) * C_ + c] = a1;
        pt[((size_t)b * K_ + 2) * C_ + c] = a2;
        pt[((size_t)b * K_ + 3) * C_ + c] = a3;
        pt[((size_t)b * K_ + 4) * C_ + c] = a4;
    }
}
__global__ void k_pt(const int* flag, const void* feat, const float* attn, float* pt) {
    __shared__ float sh[4];
    if (*flag) pt_body<true>(feat, attn, pt, sh); else pt_body<false>(feat, attn, pt, sh);
}

// ---------- 5: Kt,Vt -> W2, bias2, OV (per b,k) ----------
template<bool BF>
__device__ void prep_body(const void* qw, const void* kw, const void* kb,
                          const void* vw, const void* vb, const void* ow,
                          const void* bnw, const void* bnb, const void* bnm, const void* bnv,
                          const float* pt, float* W2, float* b2, float* OV, float* smem) {
    float* ptL = smem;            // 256
    float* KtL = smem + 256;      // 256 (pre-scaled by bn scale)
    float* VtL = smem + 512;      // 256
    float* sh  = smem + 768;      // 4
    int bk = blockIdx.x, t = threadIdx.x;   // t == output channel o
    ptL[t] = pt[(size_t)bk * C_ + t];
    __syncthreads();
    float kt = LD<BF>(kb, t), vt = LD<BF>(vb, t);
    for (int c = 0; c < C_; c++) {
        float p = ptL[c];
        kt += LD<BF>(kw, (size_t)t * C_ + c) * p;
        vt += LD<BF>(vw, (size_t)t * C_ + c) * p;
    }
    float scale = LD<BF>(bnw, t) * rsqrtf(LD<BF>(bnv, t) + 1e-5f);
    float shift = LD<BF>(bnb, t) - LD<BF>(bnm, t) * scale;
    KtL[t] = kt * scale;
    VtL[t] = vt;
    float bpart = kt * shift;
    __syncthreads();
    float ov = 0;
    for (int c = 0; c < C_; c++) ov += LD<BF>(ow, (size_t)t * C_ + c) * VtL[c];
    OV[(size_t)bk * C_ + t] = ov;
    // W2[bk][c]: t == c here; qw read coalesced (o*C + t)
    float w2 = 0;
    for (int o = 0; o < C_; o++) w2 += KtL[o] * LD<BF>(qw, (size_t)o * C_ + t);
    W2[(size_t)bk * C_ + t] = w2 * (1.0f / 16.0f);
    float bs = blk_sum(bpart, sh);
    if (t == 0) b2[bk] = bs * (1.0f / 16.0f);
}
__global__ void k_prep(const int* flag, const void* qw, const void* kw, const void* kb,
                       const void* vw, const void* vb, const void* ow,
                       const void* bnw, const void* bnb, const void* bnm, const void* bnv,
                       const float* pt, float* W2, float* b2, float* OV) {
    __shared__ float smem[772];
    if (*flag) prep_body<true >(qw, kw, kb, vw, vb, ow, bnw, bnb, bnm, bnv, pt, W2, b2, OV, smem);
    else       prep_body<false>(qw, kw, kb, vw, vb, ow, bnw, bnb, bnm, bnv, pt, W2, b2, OV, smem);
}

// ---------- 5b: diversity loss partials per b ----------
__global__ void k_div(const int* flag, const float* pt, const void* margin, float* divpart) {
    __shared__ float ptL[K_ * C_];
    __shared__ float rn[K_];
    __shared__ float cosb[32];
    __shared__ float sh[4];
    int b = blockIdx.x, t = threadIdx.x;
    for (int i = t; i < K_ * C_; i += 256) ptL[i] = pt[(size_t)b * K_ * C_ + i];
    __syncthreads();
    for (int k = 0; k < K_; k++) {
        float v = ptL[k * C_ + t];
        float s = blk_sum(v * v, sh);
        if (t == 0) rn[k] = 1.0f / fmaxf(sqrtf(s), 1e-12f);
    }
    __syncthreads();
    float m = (*flag) ? __bfloat162float(((const bf16*)margin)[0]) : ((const float*)margin)[0];
    m = fminf(fmaxf(m, 0.f), 0.5f);
    int p = t >> 3, g = t & 7;
    float contrib = 0.f;
    if (p < K_ * K_) {
        int k = p / K_, j = p % K_;
        float d = 0;
        for (int c = g; c < C_; c += 8) d += ptL[k * C_ + c] * ptL[j * C_ + c];
        d += __shfl_down(d, 4, 8);
        d += __shfl_down(d, 2, 8);
        d += __shfl_down(d, 1, 8);
        if (g == 0 && k != j) {
            float cs = d * rn[k] * rn[j];
            contrib = fmaxf(cs - m, 0.f);
        }
    }
    (void)cosb;
    float s = blk_sum(contrib, sh);
    if (t == 0) divpart[b] = s;
}

// ---------- 6: fused refine-attention + residual output ----------
template<bool BF>
__device__ void fin_body(const void* feat, const void* outb, const void* gamma,
                         const float* W2, const float* b2, const float* OV,
                         void* dout, float* smem) {
    float* W2L = smem;                  // 5*256
    float* OVL = smem + K_ * C_;        // 5*256
    float* obL = OVL + K_ * C_;         // 256
    float* b2L = obL + C_;              // 5
    int t = threadIdx.x, b = blockIdx.y;
    int n = blockIdx.x * 256 + t;
    for (int i = t; i < K_ * C_; i += 256) {
        W2L[i] = W2[(size_t)b * K_ * C_ + i];
        OVL[i] = OV[(size_t)b * K_ * C_ + i];
    }
    obL[t] = LD<BF>(outb, t);
    if (t < K_) b2L[t] = b2[b * K_ + t];
    __syncthreads();
    float g = LD<BF>(gamma, 0);
    size_t base = (size_t)b * C_ * HW_ + n;
    float l0 = b2L[0], l1 = b2L[1], l2 = b2L[2], l3 = b2L[3], l4 = b2L[4];
    for (int c = 0; c < C_; c++) {
        float f = LD<BF>(feat, base + (size_t)c * HW_);
        l0 += f * W2L[0 * C_ + c];
        l1 += f * W2L[1 * C_ + c];
        l2 += f * W2L[2 * C_ + c];
        l3 += f * W2L[3 * C_ + c];
        l4 += f * W2L[4 * C_ + c];
    }
    float mx = fmaxf(fmaxf(fmaxf(l0, l1), fmaxf(l2, l3)), l4);
    float e0 = __expf(l0 - mx), e1 = __expf(l1 - mx), e2 = __expf(l2 - mx),
          e3 = __expf(l3 - mx), e4 = __expf(l4 - mx);
    float inv = 1.0f / (e0 + e1 + e2 + e3 + e4);
    e0 *= inv; e1 *= inv; e2 *= inv; e3 *= inv; e4 *= inv;
    for (int o = 0; o < C_; o++) {
        float f = LD<BF>(feat, base + (size_t)o * HW_);
        float acc = obL[o] + e0 * OVL[0 * C_ + o] + e1 * OVL[1 * C_ + o]
                  + e2 * OVL[2 * C_ + o] + e3 * OVL[3 * C_ + o] + e4 * OVL[4 * C_ + o];
        ST<BF>(dout, base + (size_t)o * HW_, f + g * acc);
    }
}
__global__ void k_fin(const int* flag, const void* feat, const void* outb, const void* gamma,
                      const float* W2, const float* b2, const float* OV, void* dout) {
    __shared__ float smem[2 * K_ * C_ + C_ + K_];
    if (*flag) fin_body<true >(feat, outb, gamma, W2, b2, OV, dout, smem);
    else       fin_body<false>(feat, outb, gamma, W2, b2, OV, dout, smem);
}

// ---------- 7: write part_tokens + div_loss to d_out ----------
template<bool BF>
__device__ void wr_body(const float* pt, const float* divpart, void* dout) {
    int t = threadIdx.x;
    const size_t enh = (size_t)B_ * C_ * HW_;   // 33554432
    for (int i = t; i < B_ * K_ * C_; i += 256) ST<BF>(dout, enh + 1 + i, pt[i]);
    if (t == 0) {
        float s = 0;
        for (int b = 0; b < B_; b++) s += divpart[b];
        ST<BF>(dout, enh, s / (640.0f + 1e-5f));   // B*K*(K-1) + 1e-5
    }
}
__global__ void k_writer(const int* flag, const float* pt, const float* divpart, void* dout) {
    if (*flag) wr_body<true>(pt, divpart, dout); else wr_body<false>(pt, divpart, dout);
}

extern "C" void kernel_launch(void* const* d_in, const int* in_sizes, int n_in,
                              void* d_out, int out_size, void* d_ws, size_t ws_size,
                              hipStream_t stream) {
    const void* feat = d_in[0];
    const void* mask = d_in[1];
    const void* pq   = d_in[2];
    const void* temp = d_in[3];
    const void* marg = d_in[4];
    const void* qw   = d_in[5];
    const void* bnw  = d_in[6];
    const void* bnb  = d_in[7];
    const void* bnm  = d_in[8];
    const void* bnv  = d_in[9];
    const void* kw   = d_in[10];
    const void* kb   = d_in[11];
    const void* vw   = d_in[12];
    const void* vb   = d_in[13];
    const void* ow   = d_in[14];
    const void* ob   = d_in[15];
    const void* gm   = d_in[16];

    float* ws  = (float*)d_ws;
    float* sim = ws;                  // B*K*HW = 655360
    float* pt  = sim + (size_t)B_ * K_ * HW_;   // 40960
    float* qn  = pt  + B_ * K_ * C_;            // 1280
    float* W2  = qn  + K_ * C_;                 // 40960
    float* b2  = W2  + B_ * K_ * C_;            // 160
    float* OV  = b2  + B_ * K_;                 // 40960
    float* dvp = OV  + B_ * K_ * C_;            // 32
    int*  flag = (int*)(dvp + B_);

    hipLaunchKernelGGL(k_detect, dim3(1), dim3(256), 0, stream, feat, flag);
    hipLaunchKernelGGL(k_qnorm,  dim3(1), dim3(256), 0, stream, flag, pq, qn);
    hipLaunchKernelGGL(k_sim,    dim3(HW_ / 256, B_), dim3(256), 0, stream,
                       flag, feat, mask, temp, qn, sim);
    hipLaunchKernelGGL(k_softmax, dim3(B_ * K_), dim3(256), 0, stream, sim);
    hipLaunchKernelGGL(k_pt,     dim3(C_, B_), dim3(256), 0, stream, flag, feat, sim, pt);
    hipLaunchKernelGGL(k_prep,   dim3(B_ * K_), dim3(256), 0, stream,
                       flag, qw, kw, kb, vw, vb, ow, bnw, bnb, bnm, bnv, pt, W2, b2, OV);
    hipLaunchKernelGGL(k_div,    dim3(B_), dim3(256), 0, stream, flag, pt, marg, dvp);
    hipLaunchKernelGGL(k_fin,    dim3(HW_ / 256, B_), dim3(256), 0, stream,
                       flag, feat, ob, gm, W2, b2, OV, d_out);
    hipLaunchKernelGGL(k_writer, dim3(1), dim3(256), 0, stream, flag, pt, dvp, d_out);
}